// Round 4
// baseline (4997.911 us; speedup 1.0000x reference)
//
#include <hip/hip_runtime.h>
#include <cstdint>
#include <cstddef>

// SNN pipeline, np-fp32-replication strategy:
//  k1: cur1 = x@W1+b1 replicated as OpenBLAS-style fp32 k-ascending FMA chains
//      (one acc per element, sequential fmaf k=0..511), fp32 bias add, fp32 LIF
//      recurrence with numpy op order (mul,add,sub separately rounded) -> 10-bit masks.
//  k2: spike GEMM, exact 3-digit-plane f16 MFMA (integer-exact), fp32-replica LIF-2,
//      per-16-lane Wo partial dots -> po[t][32][B].
//  k3: sum partials, fp32-replica LIF-out, mean -> d_out.
// ws: w2d 6MiB @0 | s1bits 128MiB @16MiB | po 80MiB @160MiB

typedef _Float16 f16;
typedef _Float16 f16x8 __attribute__((ext_vector_type(8)));
typedef float f32x4 __attribute__((ext_vector_type(4)));
typedef int i32x4 __attribute__((ext_vector_type(4)));

#define MFMA16(A, B, C) __builtin_amdgcn_mfma_f32_16x16x32_f16(A, B, C, 0, 0, 0)

static constexpr int BSZ = 65536;
static constexpr int IN = 512;
static constexpr int H = 1024;

static constexpr double K11 = 4.8828125e-04;                // 2^-11
static constexpr double K22 = 2.384185791015625e-07;        // 2^-22
static constexpr double K33 = 1.1641532182693481e-10;       // 2^-33

// Split src[K][1024] fp32 into 3 balanced 11-bit digits on 2^-33 grid,
// transposed to dst[digit][j 1024][k K] (f16 integers, exact).
__global__ void prep_digits(const float* __restrict__ src, f16* __restrict__ dst, int K) {
    int idx = blockIdx.x * 256 + threadIdx.x;
    int k = idx >> 10;
    int j = idx & 1023;
    if (k >= K) return;
    float v = src[(size_t)k * 1024 + j];
    v = fminf(fmaxf(v, -0.24f), 0.24f);
    int u = (int)rint((double)v * 8589934592.0);  // 2^33
    int d3 = ((u + 1024) & 2047) - 1024; u = (u - d3) >> 11;
    int d2 = ((u + 1024) & 2047) - 1024; u = (u - d2) >> 11;
    size_t plane = (size_t)1024 * K;
    size_t o = (size_t)j * K + k;
    dst[o] = (f16)(float)u;
    dst[o + plane] = (f16)(float)d2;
    dst[o + 2 * plane] = (f16)(float)d3;
}

// k1: fp32 k-ordered FMA-chain GEMM (BLAS-replica) + fp32-replica LIF -> spike masks.
// tile 64 b-rows x 256 h-cols, 256 threads = 16 ht x 16 bt, thread = 4b x 16h.
__global__ __launch_bounds__(256, 2) void k1_chain(
    const float* __restrict__ x, const float* __restrict__ w1,
    const float* __restrict__ b1, unsigned short* __restrict__ s1b) {
    __shared__ float xs[32][65];    // [k][b] (+1 pad)
    __shared__ float ws[32][256];   // [k][h]
    const int hblk = blockIdx.x;    // 4
    const int bblk = blockIdx.y;    // 1024
    const int tid = threadIdx.x;
    const int ht = tid & 15, bt = tid >> 4;
    const int h0 = hblk * 256, b0 = bblk * 64;

    float acc[4][16] = {};

    for (int kc = 0; kc < 512; kc += 32) {
        float4 xv[2], wv[8];
#pragma unroll
        for (int i = 0; i < 2; ++i) {
            int idx = tid + 256 * i;            // 512 f4: 64 rows x 8 segs
            int br = idx >> 3, ks = idx & 7;
            xv[i] = *(const float4*)&x[(size_t)(b0 + br) * IN + kc + ks * 4];
        }
#pragma unroll
        for (int i = 0; i < 8; ++i) {
            int idx = tid + 256 * i;            // 2048 f4: 32 rows x 64 segs
            int kr = idx >> 6, c4 = idx & 63;
            wv[i] = *(const float4*)&w1[(size_t)(kc + kr) * H + h0 + c4 * 4];
        }
        __syncthreads();
#pragma unroll
        for (int i = 0; i < 2; ++i) {
            int idx = tid + 256 * i;
            int br = idx >> 3, ks = idx & 7;
            xs[ks * 4 + 0][br] = xv[i].x;
            xs[ks * 4 + 1][br] = xv[i].y;
            xs[ks * 4 + 2][br] = xv[i].z;
            xs[ks * 4 + 3][br] = xv[i].w;
        }
#pragma unroll
        for (int i = 0; i < 8; ++i) {
            int idx = tid + 256 * i;
            int kr = idx >> 6, c4 = idx & 63;
            *(float4*)&ws[kr][c4 * 4] = wv[i];
        }
        __syncthreads();
#pragma unroll
        for (int k = 0; k < 32; ++k) {
            float xr[4];
#pragma unroll
            for (int i = 0; i < 4; ++i) xr[i] = xs[k][bt * 4 + i];
            float wr[16];
#pragma unroll
            for (int g = 0; g < 4; ++g) {
                float4 t = *(const float4*)&ws[k][ht * 16 + g * 4];
                wr[g * 4 + 0] = t.x; wr[g * 4 + 1] = t.y;
                wr[g * 4 + 2] = t.z; wr[g * 4 + 3] = t.w;
            }
#pragma unroll
            for (int i = 0; i < 4; ++i)
#pragma unroll
                for (int j = 0; j < 16; ++j)
                    acc[i][j] = fmaf(xr[i], wr[j], acc[i][j]);  // strict k-order chain
        }
    }

    float b1v[16];
#pragma unroll
    for (int j = 0; j < 16; ++j) b1v[j] = b1[h0 + ht * 16 + j];
#pragma unroll
    for (int i = 0; i < 4; ++i) {
        unsigned short outb[16];
#pragma unroll
        for (int j = 0; j < 16; ++j) {
            float c = __fadd_rn(acc[i][j], b1v[j]);
            float m = 0.0f;
            unsigned bits = 0u;
#pragma unroll
            for (int t = 0; t < 10; ++t) {
                float rst = (m > 1.0f) ? 1.0f : 0.0f;
                m = __fmul_rn(0.9f, m);   // np: BETA*mem (rounded)
                m = __fadd_rn(m, c);      // np: + inp   (rounded)
                m = __fsub_rn(m, rst);    // np: - reset (rounded)
                if (m > 1.0f) bits |= (1u << t);
            }
            outb[j] = (unsigned short)bits;
        }
        size_t off = (size_t)(b0 + bt * 4 + i) * H + h0 + ht * 16;
        *(int4*)&s1b[off] = ((const int4*)outb)[0];
        *(int4*)&s1b[off + 8] = ((const int4*)outb)[1];
    }
}

// k2: spike GEMM, 10 steps x 3 digit planes, exact fp32 digit sums,
// fp32-replica LIF-2, Wo partial dots -> po.
__global__ __launch_bounds__(256, 2) void k2_spikes_gemm(
    const unsigned short* __restrict__ s1bits, const f16* __restrict__ w2d,
    const float* __restrict__ b2, const float* __restrict__ wo,
    float* __restrict__ po) {
    __shared__ unsigned short Asl[32][40];
    __shared__ f16 Bsl[3][32][40];
    __shared__ double pored[32];
    const int jblk = blockIdx.x, bblk = blockIdx.y;
    const int tid = threadIdx.x;
    const int lane = tid & 63, wave = tid >> 6;
    const int wr = wave >> 1, wc = wave & 1;
    const int l15 = lane & 15, loct = lane >> 4;

    f32x4 acc[10][3] = {};

    for (int kc = 0; kc < H; kc += 32) {
        int pl0 = tid >> 7, i0 = tid & 127;
        const f16* bsrc0 = w2d + (size_t)pl0 * H * H + (size_t)(jblk * 32 + (i0 >> 2)) * H + kc + (i0 & 3) * 8;
        f16x8 bv0 = *(const f16x8*)bsrc0;
        f16x8 bv1;
        i32x4 av;
        if (tid < 128) {
            int i1 = (256 + tid) & 127;
            const f16* bsrc1 = w2d + (size_t)2 * H * H + (size_t)(jblk * 32 + (i1 >> 2)) * H + kc + (i1 & 3) * 8;
            bv1 = *(const f16x8*)bsrc1;
        } else {
            int ia = tid - 128;
            av = *(const i32x4*)(s1bits + (size_t)(bblk * 32 + (ia >> 2)) * H + kc + (ia & 3) * 8);
        }
        __syncthreads();
        *(f16x8*)&Bsl[pl0][i0 >> 2][(i0 & 3) * 8] = bv0;
        if (tid < 128) {
            int i1 = (256 + tid) & 127;
            *(f16x8*)&Bsl[2][i1 >> 2][(i1 & 3) * 8] = bv1;
        } else {
            int ia = tid - 128;
            *(i32x4*)&Asl[ia >> 2][(ia & 3) * 8] = av;
        }
        __syncthreads();
        i32x4 am = *(const i32x4*)&Asl[wr * 16 + l15][loct * 8];
        f16x8 bf0 = *(const f16x8*)&Bsl[0][wc * 16 + l15][loct * 8];
        f16x8 bf1 = *(const f16x8*)&Bsl[1][wc * 16 + l15][loct * 8];
        f16x8 bf2 = *(const f16x8*)&Bsl[2][wc * 16 + l15][loct * 8];
#pragma unroll
        for (int t = 0; t < 10; ++t) {
            union { i32x4 i; f16x8 h; } u;
#pragma unroll
            for (int q = 0; q < 4; ++q)
                u.i[q] = (int)((((unsigned)am[q] >> t) & 0x00010001u) * 0x3C00u);
            acc[t][0] = MFMA16(u.h, bf0, acc[t][0]);
            acc[t][1] = MFMA16(u.h, bf1, acc[t][1]);
            acc[t][2] = MFMA16(u.h, bf2, acc[t][2]);
        }
    }
    // epilogue: exact digit combine -> fp32, fp32-replica LIF-2, Wo partial reduce
    int col = jblk * 32 + wc * 16 + l15;
    float b2v = b2[col];
    double wov = (double)wo[col];
    int rowbase = bblk * 32 + wr * 16 + loct * 4;
    float m2[4] = {0.0f, 0.0f, 0.0f, 0.0f};
#pragma unroll
    for (int t = 0; t < 10; ++t) {
        double psum[4];
#pragma unroll
        for (int r = 0; r < 4; ++r) {
            float inp = (float)((double)acc[t][0][r] * K11 + (double)acc[t][1][r] * K22
                                + (double)acc[t][2][r] * K33);
            inp = __fadd_rn(inp, b2v);
            float rst = (m2[r] > 1.0f) ? 1.0f : 0.0f;
            m2[r] = __fmul_rn(0.9f, m2[r]);
            m2[r] = __fadd_rn(m2[r], inp);
            m2[r] = __fsub_rn(m2[r], rst);
            double pv = (m2[r] > 1.0f) ? wov : 0.0;
            pv += __shfl_xor(pv, 1);
            pv += __shfl_xor(pv, 2);
            pv += __shfl_xor(pv, 4);
            pv += __shfl_xor(pv, 8);
            psum[r] = pv;
        }
        if (wc == 1 && l15 == 0) {
#pragma unroll
            for (int r = 0; r < 4; ++r) pored[wr * 16 + loct * 4 + r] = psum[r];
        }
        __syncthreads();
        if (wc == 0 && l15 == 0) {
#pragma unroll
            for (int r = 0; r < 4; ++r)
                po[(size_t)(t * 32 + jblk) * BSZ + rowbase + r] =
                    (float)(psum[r] + pored[wr * 16 + loct * 4 + r]);
        }
        __syncthreads();
    }
}

// k3: sum 32 partials (ascending j-blocks), fp32-replica LIF-out, mean.
__global__ void k3_out(const float* __restrict__ po, const float* __restrict__ bo,
                       float* __restrict__ out) {
    int b = blockIdx.x * 256 + threadIdx.x;
    float mo = 0.0f, s = 0.0f;
    float bov = bo[0];
    for (int t = 0; t < 10; ++t) {
        float inp = 0.0f;
#pragma unroll
        for (int jb = 0; jb < 32; ++jb) inp += po[(size_t)(t * 32 + jb) * BSZ + b];
        inp = __fadd_rn(inp, bov);
        float rst = (mo > 1.0f) ? 1.0f : 0.0f;
        mo = __fmul_rn(0.9f, mo);
        mo = __fadd_rn(mo, inp);
        mo = __fsub_rn(mo, rst);
        s += mo;
    }
    out[b] = s / 10.0f;
}

extern "C" void kernel_launch(void* const* d_in, const int* in_sizes, int n_in,
                              void* d_out, int out_size, void* d_ws, size_t ws_size,
                              hipStream_t stream) {
    (void)in_sizes; (void)n_in; (void)out_size; (void)ws_size;
    const float* x  = (const float*)d_in[0];
    const float* W1 = (const float*)d_in[1];
    const float* b1 = (const float*)d_in[2];
    const float* W2 = (const float*)d_in[3];
    const float* b2 = (const float*)d_in[4];
    const float* Wo = (const float*)d_in[5];
    const float* bo = (const float*)d_in[6];
    float* out = (float*)d_out;

    char* ws = (char*)d_ws;
    f16* w2d = (f16*)ws;                                                   // 6 MiB @ 0
    unsigned short* s1bits = (unsigned short*)(ws + ((size_t)16 << 20));   // 128 MiB
    float* po = (float*)(ws + ((size_t)160 << 20));                        // 80 MiB

    prep_digits<<<dim3((H * 1024) / 256), 256, 0, stream>>>(W2, w2d, H);
    k1_chain<<<dim3(4, BSZ / 64), 256, 0, stream>>>(x, W1, b1, s1bits);
    k2_spikes_gemm<<<dim3(H / 32, BSZ / 32), 256, 0, stream>>>(s1bits, w2d, b2, Wo, po);
    k3_out<<<dim3(BSZ / 256), 256, 0, stream>>>(po, bo, out);
}

// Round 5
// 3582.496 us; speedup vs baseline: 1.3951x; 1.3951x over previous
//
#include <hip/hip_runtime.h>
#include <cstdint>
#include <cstddef>

// SNN pipeline, np-fp32-replication strategy (round 5):
//  k1: cur1 = x@W1+b1 as fp32 k-ascending FMA chains (OpenBLAS replica) + fp32-replica
//      LIF-1 -> packed 10-bit spike masks (unchanged from round 4, passed).
//  k2: spike GEMM, 2-plane Dekker f16 split of W2 (hi + lo*2^11; fp32-chain noise ~= np's
//      own sgemm noise). Block 64 rows x 32 cols, wave = unique 16 rows x 32 cols:
//      one bitmask unpack feeds 40 MFMAs (10 t x 2 planes x 2 col-frags), zero
//      redundant unpack. A masks direct from global; B double-buffered in LDS,
//      ONE barrier per K-iter. fp32-replica LIF-2 in regs, shfl-reduced Wo partials.
//  k3: sum 32 partials, fp32-replica LIF-out, mean -> d_out.
// ws: w2d 4MiB @0 | s1bits 128MiB @16MiB | po 80MiB @160MiB

typedef _Float16 f16;
typedef _Float16 f16x8 __attribute__((ext_vector_type(8)));
typedef float f32x4 __attribute__((ext_vector_type(4)));
typedef int i32x4 __attribute__((ext_vector_type(4)));

#define MFMA16(A, B, C) __builtin_amdgcn_mfma_f32_16x16x32_f16(A, B, C, 0, 0, 0)

static constexpr int BSZ = 65536;
static constexpr int IN = 512;
static constexpr int H = 1024;

// W2[k][j] fp32 -> w2d[plane][j][k] f16 Dekker limbs: plane0 = f16(w),
// plane1 = f16((w - hi) * 2^11)  (scaled into f16 normal range).
__global__ void prep_dekker(const float* __restrict__ src, f16* __restrict__ dst) {
    int idx = blockIdx.x * 256 + threadIdx.x;
    int k = idx >> 10;
    int j = idx & 1023;
    float w = src[(size_t)k * 1024 + j];
    f16 hi = (f16)w;
    float lo = (w - (float)hi) * 2048.0f;
    size_t o = (size_t)j * 1024 + k;
    dst[o] = hi;
    dst[o + (size_t)H * H] = (f16)lo;
}

// k1: fp32 k-ordered FMA-chain GEMM (BLAS-replica) + fp32-replica LIF -> spike masks.
// tile 64 b-rows x 256 h-cols, 256 threads = 16 ht x 16 bt, thread = 4b x 16h.
__global__ __launch_bounds__(256, 2) void k1_chain(
    const float* __restrict__ x, const float* __restrict__ w1,
    const float* __restrict__ b1, unsigned short* __restrict__ s1b) {
    __shared__ float xs[32][65];    // [k][b] (+1 pad)
    __shared__ float ws[32][256];   // [k][h]
    const int hblk = blockIdx.x;    // 4
    const int bblk = blockIdx.y;    // 1024
    const int tid = threadIdx.x;
    const int ht = tid & 15, bt = tid >> 4;
    const int h0 = hblk * 256, b0 = bblk * 64;

    float acc[4][16] = {};

    for (int kc = 0; kc < 512; kc += 32) {
        float4 xv[2], wv[8];
#pragma unroll
        for (int i = 0; i < 2; ++i) {
            int idx = tid + 256 * i;            // 512 f4: 64 rows x 8 segs
            int br = idx >> 3, ks = idx & 7;
            xv[i] = *(const float4*)&x[(size_t)(b0 + br) * IN + kc + ks * 4];
        }
#pragma unroll
        for (int i = 0; i < 8; ++i) {
            int idx = tid + 256 * i;            // 2048 f4: 32 rows x 64 segs
            int kr = idx >> 6, c4 = idx & 63;
            wv[i] = *(const float4*)&w1[(size_t)(kc + kr) * H + h0 + c4 * 4];
        }
        __syncthreads();
#pragma unroll
        for (int i = 0; i < 2; ++i) {
            int idx = tid + 256 * i;
            int br = idx >> 3, ks = idx & 7;
            xs[ks * 4 + 0][br] = xv[i].x;
            xs[ks * 4 + 1][br] = xv[i].y;
            xs[ks * 4 + 2][br] = xv[i].z;
            xs[ks * 4 + 3][br] = xv[i].w;
        }
#pragma unroll
        for (int i = 0; i < 8; ++i) {
            int idx = tid + 256 * i;
            int kr = idx >> 6, c4 = idx & 63;
            *(float4*)&ws[kr][c4 * 4] = wv[i];
        }
        __syncthreads();
#pragma unroll
        for (int k = 0; k < 32; ++k) {
            float xr[4];
#pragma unroll
            for (int i = 0; i < 4; ++i) xr[i] = xs[k][bt * 4 + i];
            float wr[16];
#pragma unroll
            for (int g = 0; g < 4; ++g) {
                float4 t = *(const float4*)&ws[k][ht * 16 + g * 4];
                wr[g * 4 + 0] = t.x; wr[g * 4 + 1] = t.y;
                wr[g * 4 + 2] = t.z; wr[g * 4 + 3] = t.w;
            }
#pragma unroll
            for (int i = 0; i < 4; ++i)
#pragma unroll
                for (int j = 0; j < 16; ++j)
                    acc[i][j] = fmaf(xr[i], wr[j], acc[i][j]);  // strict k-order chain
        }
    }

    float b1v[16];
#pragma unroll
    for (int j = 0; j < 16; ++j) b1v[j] = b1[h0 + ht * 16 + j];
#pragma unroll
    for (int i = 0; i < 4; ++i) {
        unsigned short outb[16];
#pragma unroll
        for (int j = 0; j < 16; ++j) {
            float c = __fadd_rn(acc[i][j], b1v[j]);
            float m = 0.0f;
            unsigned bits = 0u;
#pragma unroll
            for (int t = 0; t < 10; ++t) {
                float rst = (m > 1.0f) ? 1.0f : 0.0f;
                m = __fmul_rn(0.9f, m);
                m = __fadd_rn(m, c);
                m = __fsub_rn(m, rst);
                if (m > 1.0f) bits |= (1u << t);
            }
            outb[j] = (unsigned short)bits;
        }
        size_t off = (size_t)(b0 + bt * 4 + i) * H + h0 + ht * 16;
        *(int4*)&s1b[off] = ((const int4*)outb)[0];
        *(int4*)&s1b[off + 8] = ((const int4*)outb)[1];
    }
}

// k2: spike GEMM. Block = 64 rows x 32 cols; wave = 16 rows x 32 cols (2 col-frags).
// A masks direct global; B (2 Dekker planes) double-buffered in LDS, 1 barrier/iter.
__global__ __launch_bounds__(256, 2) void k2_spikes_gemm(
    const unsigned short* __restrict__ s1bits, const f16* __restrict__ w2d,
    const float* __restrict__ b2, const float* __restrict__ wo,
    float* __restrict__ po) {
    __shared__ f16 Bs[2][2][32][40];   // [buf][plane][j][k] stride 40 (80B rows, 2-way max)
    const int jblk = blockIdx.x, bblk = blockIdx.y;
    const int tid = threadIdx.x;
    const int lane = tid & 63, wave = tid >> 6;
    const int l15 = lane & 15, loct = lane >> 4;
    const int sp = tid >> 7, sj = (tid >> 2) & 31, ss = tid & 3;   // staging ids

    const f16* bsrc = w2d + (size_t)sp * H * H + (size_t)(jblk * 32 + sj) * 1024 + ss * 8;
    const unsigned short* asrc =
        s1bits + (size_t)(bblk * 64 + wave * 16 + l15) * 1024 + loct * 8;

    f32x4 acc[10][2][2] = {};   // [t][plane][colfrag]

    f16x8 gb = *(const f16x8*)bsrc;
    i32x4 ga = *(const i32x4*)asrc;
    int buf = 0;
    for (int kc = 0; kc < 1024; kc += 32) {
        *(f16x8*)&Bs[buf][sp][sj][ss * 8] = gb;
        int kn = (kc + 32 < 1024) ? (kc + 32) : 0;   // last-iter dummy reload
        f16x8 gbn = *(const f16x8*)(bsrc + kn);
        i32x4 gan = *(const i32x4*)(asrc + kn);
        __syncthreads();
        f16x8 bf[2][2];
#pragma unroll
        for (int p = 0; p < 2; ++p)
#pragma unroll
            for (int cf = 0; cf < 2; ++cf)
                bf[p][cf] = *(const f16x8*)&Bs[buf][p][cf * 16 + l15][loct * 8];
#pragma unroll
        for (int t = 0; t < 10; ++t) {
            union { i32x4 i; f16x8 h; } u;
#pragma unroll
            for (int q = 0; q < 4; ++q)
                u.i[q] = (int)((((unsigned)ga[q] >> t) & 0x00010001u) * 0x3C00u);
            acc[t][0][0] = MFMA16(u.h, bf[0][0], acc[t][0][0]);
            acc[t][0][1] = MFMA16(u.h, bf[0][1], acc[t][0][1]);
            acc[t][1][0] = MFMA16(u.h, bf[1][0], acc[t][1][0]);
            acc[t][1][1] = MFMA16(u.h, bf[1][1], acc[t][1][1]);
        }
        gb = gbn; ga = gan;
        buf ^= 1;
    }

    // epilogue: Dekker combine, fp32-replica LIF-2, in-wave Wo partial reduce
    int col0 = jblk * 32 + l15;
    float b2v0 = b2[col0], b2v1 = b2[col0 + 16];
    double wov0 = (double)wo[col0], wov1 = (double)wo[col0 + 16];
    int rowb = bblk * 64 + wave * 16 + loct * 4;
    float m2a[4] = {0.0f, 0.0f, 0.0f, 0.0f};
    float m2b[4] = {0.0f, 0.0f, 0.0f, 0.0f};
#pragma unroll
    for (int t = 0; t < 10; ++t) {
#pragma unroll
        for (int r = 0; r < 4; ++r) {
            float i0 = (float)((double)acc[t][0][0][r] + (double)acc[t][1][0][r] * 4.8828125e-4);
            i0 = __fadd_rn(i0, b2v0);
            float rst0 = (m2a[r] > 1.0f) ? 1.0f : 0.0f;
            m2a[r] = __fmul_rn(0.9f, m2a[r]);
            m2a[r] = __fadd_rn(m2a[r], i0);
            m2a[r] = __fsub_rn(m2a[r], rst0);
            float i1 = (float)((double)acc[t][0][1][r] + (double)acc[t][1][1][r] * 4.8828125e-4);
            i1 = __fadd_rn(i1, b2v1);
            float rst1 = (m2b[r] > 1.0f) ? 1.0f : 0.0f;
            m2b[r] = __fmul_rn(0.9f, m2b[r]);
            m2b[r] = __fadd_rn(m2b[r], i1);
            m2b[r] = __fsub_rn(m2b[r], rst1);
            double pv = ((m2a[r] > 1.0f) ? wov0 : 0.0) + ((m2b[r] > 1.0f) ? wov1 : 0.0);
            pv += __shfl_xor(pv, 1);
            pv += __shfl_xor(pv, 2);
            pv += __shfl_xor(pv, 4);
            pv += __shfl_xor(pv, 8);
            if (l15 == r)
                po[(size_t)(t * 32 + jblk) * BSZ + rowb + r] = (float)pv;
        }
    }
}

// k3: sum 32 partials (ascending j-blocks), fp32-replica LIF-out, mean.
__global__ void k3_out(const float* __restrict__ po, const float* __restrict__ bo,
                       float* __restrict__ out) {
    int b = blockIdx.x * 256 + threadIdx.x;
    float mo = 0.0f, s = 0.0f;
    float bov = bo[0];
    for (int t = 0; t < 10; ++t) {
        float inp = 0.0f;
#pragma unroll
        for (int jb = 0; jb < 32; ++jb) inp += po[(size_t)(t * 32 + jb) * BSZ + b];
        inp = __fadd_rn(inp, bov);
        float rst = (mo > 1.0f) ? 1.0f : 0.0f;
        mo = __fmul_rn(0.9f, mo);
        mo = __fadd_rn(mo, inp);
        mo = __fsub_rn(mo, rst);
        s += mo;
    }
    out[b] = s / 10.0f;
}

extern "C" void kernel_launch(void* const* d_in, const int* in_sizes, int n_in,
                              void* d_out, int out_size, void* d_ws, size_t ws_size,
                              hipStream_t stream) {
    (void)in_sizes; (void)n_in; (void)out_size; (void)ws_size;
    const float* x  = (const float*)d_in[0];
    const float* W1 = (const float*)d_in[1];
    const float* b1 = (const float*)d_in[2];
    const float* W2 = (const float*)d_in[3];
    const float* b2 = (const float*)d_in[4];
    const float* Wo = (const float*)d_in[5];
    const float* bo = (const float*)d_in[6];
    float* out = (float*)d_out;

    char* ws = (char*)d_ws;
    f16* w2d = (f16*)ws;                                                   // 4 MiB @ 0
    unsigned short* s1bits = (unsigned short*)(ws + ((size_t)16 << 20));   // 128 MiB
    float* po = (float*)(ws + ((size_t)160 << 20));                        // 80 MiB

    prep_dekker<<<dim3((H * H) / 256), 256, 0, stream>>>(W2, w2d);
    k1_chain<<<dim3(4, BSZ / 64), 256, 0, stream>>>(x, W1, b1, s1bits);
    k2_spikes_gemm<<<dim3(H / 32, BSZ / 64), 256, 0, stream>>>(s1bits, w2d, b2, Wo, po);
    k3_out<<<dim3(BSZ / 256), 256, 0, stream>>>(po, bo, out);
}